// Round 1
// 186.907 us; speedup vs baseline: 1.0191x; 1.0191x over previous
//
#include <hip/hip_runtime.h>
#include <hip/hip_bf16.h>

// MHA layer: B=2 S=2048 D=1024 H=16 HD=64. fp32 accum, bf16 MFMA internally.
// prep (W transpose only) -> fused QKV GEMM (128x128, A staged directly from
// x with inline dtype handling; Q scaled by 1/8*log2e so attn uses exp2
// directly) -> flash attention (q-tile 128, 8 waves x 16 q-rows, 512 thr,
// double-buffered LDS K/V with prefetch-before-compute, S^T MFMA + packed P,
// ones-MFMA lsum) -> out GEMM (64x128). dtype flag computed inline per kernel.

#define S_ 2048
#define D_ 1024
#define HD_ 64
#define LDSW 72      // padded LDS row stride (shorts) for Ps/Ts
#define QSZ 4194304  // shorts per Q/K/V buffer (32*2048*64)

typedef __attribute__((ext_vector_type(8))) short bf16x8;
typedef __attribute__((ext_vector_type(4))) float f32x4;

static __device__ __forceinline__ short f2bs(float f) {
    __hip_bfloat16 h = __float2bfloat16(f);
    return *reinterpret_cast<short*>(&h);
}
static __device__ __forceinline__ float bs2f(short s) {
    __hip_bfloat16 h = *reinterpret_cast<__hip_bfloat16*>(&s);
    return __bfloat162float(h);
}
static __device__ __forceinline__ bf16x8 cvt8(const float* p) {
    f32x4 u0 = *(const f32x4*)p;
    f32x4 u1 = *(const f32x4*)(p + 4);
    bf16x8 r;
    r[0] = f2bs(u0[0]); r[1] = f2bs(u0[1]); r[2] = f2bs(u0[2]); r[3] = f2bs(u0[3]);
    r[4] = f2bs(u1[0]); r[5] = f2bs(u1[1]); r[6] = f2bs(u1[2]); r[7] = f2bs(u1[3]);
    return r;
}
// async global->LDS, 16B per lane; LDS dest = base + lane*16 (wave-uniform base)
static __device__ __forceinline__ void gld16(const void* g, void* l) {
    __builtin_amdgcn_global_load_lds(
        (const __attribute__((address_space(1))) unsigned int*)g,
        (__attribute__((address_space(3))) unsigned int*)l, 16, 0, 0);
}
// inline dtype detect: 1 if x is fp32, 0 if bf16. Wave-uniform.
static __device__ __forceinline__ int detect_f32(const unsigned int* __restrict__ xw) {
    const unsigned int w = xw[threadIdx.x & 63];
    const int e = (int)((w >> 7) & 0xFFu);
    unsigned long long m = __ballot(e >= 117 && e <= 130);
    return (__popcll(m) >= 32) ? 0 : 1;
}

// ---------------------------------------------------------------------------
// prep: 1024 blocks transpose the 4 weight matrices [1024][1024] -> Wt[n][k]
// ---------------------------------------------------------------------------
__global__ __launch_bounds__(256) void prep(
    const void* __restrict__ x,  // only for dtype detection
    const void* __restrict__ w0, const void* __restrict__ w1,
    const void* __restrict__ w2, const void* __restrict__ w3,
    short* __restrict__ Wt)
{
    __shared__ __align__(16) short Ts[64 * LDSW];
    const int f32in = detect_f32((const unsigned int*)x);
    const int idx = blockIdx.x;
    const int z = idx >> 8, bb = idx & 255;
    const void* W = z == 0 ? w0 : z == 1 ? w1 : z == 2 ? w2 : w3;
    short* O = Wt + (size_t)z * D_ * D_;
    const int k0 = (bb & 15) * 64, n0 = (bb >> 4) * 64;
    const int t = threadIdx.x;
    const int row = t >> 2, seg = t & 3;

    if (f32in) {
        const float* wg = (const float*)W + (size_t)(k0 + row) * D_ + n0;
        *(bf16x8*)&Ts[row * LDSW + seg * 8]      = cvt8(wg + seg * 8);
        *(bf16x8*)&Ts[row * LDSW + seg * 8 + 32] = cvt8(wg + seg * 8 + 32);
    } else {
        const short* wg = (const short*)W + (size_t)(k0 + row) * D_ + n0;
        *(bf16x8*)&Ts[row * LDSW + seg * 8]      = *(const bf16x8*)(wg + seg * 8);
        *(bf16x8*)&Ts[row * LDSW + seg * 8 + 32] = *(const bf16x8*)(wg + seg * 8 + 32);
    }
    __syncthreads();

    short* og = O + (size_t)(n0 + row) * D_ + k0;
    #pragma unroll
    for (int g = 0; g < 2; ++g) {
        const int ks = seg * 8 + g * 32;
        alignas(16) short tmp[8];
        #pragma unroll
        for (int i = 0; i < 8; ++i) tmp[i] = Ts[(ks + i) * LDSW + row];
        *(bf16x8*)(og + ks) = *(const bf16x8*)tmp;
    }
}

// ---------------------------------------------------------------------------
// Fused QKV GEMM: Wt3 = [3072][1024] bf16 (Wq^T|Wk^T|Wv^T contiguous).
// A staged DIRECTLY from x: bf16 -> gld16, fp32 -> load+cvt+ds_write_b128
// (same LDS dest/swizzle). 128x128 tile, grid (32,24) = 768 blocks.
// id = n0>>10: 0->Q (scale 1/8*log2e, head-split), 1->K (head-split),
// 2->V (transp).
// ---------------------------------------------------------------------------
__global__ __launch_bounds__(256) void gemm_qkv(
    const void* __restrict__ X, const short* __restrict__ Wt3,
    const void* __restrict__ bq, const void* __restrict__ bk,
    const void* __restrict__ bv, short* __restrict__ out)
{
    __shared__ __align__(16) short As[128 * 64];
    __shared__ __align__(16) short Bs[128 * 64];
    const int ext_f32 = detect_f32((const unsigned int*)X);
    const int t = threadIdx.x;
    const int wave = t >> 6, lane = t & 63;
    const int quad = lane >> 4, l16 = lane & 15;
    const int wm = wave & 1, wn = wave >> 1;
    const int m0 = blockIdx.x * 128, n0 = blockIdx.y * 128;
    const int id = n0 >> 10;
    const int lr = lane >> 3;
    const int kx = ((lane & 7) ^ (lr & 7)) * 8;

    f32x4 acc[4][4];
    #pragma unroll
    for (int i = 0; i < 4; ++i)
        #pragma unroll
        for (int j = 0; j < 4; ++j) acc[i][j] = (f32x4){0.f, 0.f, 0.f, 0.f};

    // A element offset for lane: row m0+wave*32+i*8+lr, col k0+kx
    const size_t arow = (size_t)(m0 + wave * 32 + lr) * D_ + kx;
    const short* Bb = Wt3 + (size_t)(n0 + wave * 32 + lr) * D_ + kx;

    for (int kb = 0; kb < 16; ++kb) {
        __syncthreads();
        const int k0 = kb * 64;
        if (ext_f32) {
            const float* Xf = (const float*)X;
            #pragma unroll
            for (int i = 0; i < 4; ++i)
                *(bf16x8*)&As[(wave * 4 + i) * 512 + lane * 8] =
                    cvt8(Xf + arow + (size_t)i * 8 * D_ + k0);
        } else {
            const short* Xs = (const short*)X;
            #pragma unroll
            for (int i = 0; i < 4; ++i)
                gld16(Xs + arow + (size_t)i * 8 * D_ + k0, &As[(wave * 4 + i) * 512]);
        }
        #pragma unroll
        for (int i = 0; i < 4; ++i)
            gld16(Bb + (size_t)i * 8 * D_ + k0, &Bs[(wave * 4 + i) * 512]);
        __syncthreads();

        #pragma unroll
        for (int ks = 0; ks < 2; ++ks) {
            const int sw = ((ks * 4 + quad) ^ (l16 & 7)) * 8;
            bf16x8 af[4], bfr[4];
            #pragma unroll
            for (int i = 0; i < 4; ++i) {
                af[i]  = *(const bf16x8*)&As[(wm * 64 + i * 16 + l16) * 64 + sw];
                bfr[i] = *(const bf16x8*)&Bs[(wn * 64 + i * 16 + l16) * 64 + sw];
            }
            #pragma unroll
            for (int mi = 0; mi < 4; ++mi)
                #pragma unroll
                for (int ni = 0; ni < 4; ++ni)
                    acc[mi][ni] = __builtin_amdgcn_mfma_f32_16x16x32_bf16(
                        af[mi], bfr[ni], acc[mi][ni], 0, 0, 0);
        }
    }

    const void* bias = id == 0 ? bq : id == 1 ? bk : bv;
    // Q pre-scale folds softmax 1/sqrt(HD)=0.125 AND log2(e), so attn's
    // exp(x) becomes a bare exp2 on the MFMA output.
    const float oscale = id == 0 ? 0.18033688011112042f : 1.0f;
    #pragma unroll
    for (int ni = 0; ni < 4; ++ni) {
        const int n = n0 + wn * 64 + ni * 16 + l16;
        const int nl = n & 1023, h = nl >> 6, d = nl & 63;
        const float bvl = ext_f32 ? ((const float*)bias)[nl]
                                  : bs2f(((const short*)bias)[nl]);
        #pragma unroll
        for (int mi = 0; mi < 4; ++mi)
            #pragma unroll
            for (int r = 0; r < 4; ++r) {
                const int m = m0 + wm * 64 + mi * 16 + quad * 4 + r;
                const int b = m >> 11, s = m & 2047;
                const int bh = b * 16 + h;
                const float v = (acc[mi][ni][r] + bvl) * oscale;
                const size_t idx = (id < 2)
                    ? (size_t)id * QSZ + ((size_t)bh * S_ + s) * HD_ + d
                    : (size_t)2 * QSZ + ((size_t)bh * HD_ + d) * S_ + s;
                out[idx] = f2bs(v);
            }
    }
}

// ---------------------------------------------------------------------------
// Output GEMM: C[m][n] = sum_k A[m][k]*Bt[n][k] + bias[n], C external dtype.
// 64x128 tile, grid (64,8) = 512 blocks.
// ---------------------------------------------------------------------------
__global__ __launch_bounds__(256) void gemm_out(
    const short* __restrict__ A, const short* __restrict__ Bt,
    const void* __restrict__ bias, void* __restrict__ C,
    const unsigned int* __restrict__ xw)
{
    __shared__ __align__(16) short As[64 * 64];
    __shared__ __align__(16) short Bs[128 * 64];
    const int ext_f32 = detect_f32(xw);
    const int t = threadIdx.x;
    const int wave = t >> 6, lane = t & 63;
    const int quad = lane >> 4, l16 = lane & 15;
    const int wm = wave & 1, wn = wave >> 1;
    const int m0 = blockIdx.x * 64, n0 = blockIdx.y * 128;
    const int lr = lane >> 3;
    const int kx = ((lane & 7) ^ (lr & 7)) * 8;

    f32x4 acc[2][4];
    #pragma unroll
    for (int i = 0; i < 2; ++i)
        #pragma unroll
        for (int j = 0; j < 4; ++j) acc[i][j] = (f32x4){0.f, 0.f, 0.f, 0.f};

    const short* Ab = A  + (size_t)(m0 + wave * 16 + lr) * D_ + kx;
    const short* Bb = Bt + (size_t)(n0 + wave * 32 + lr) * D_ + kx;

    for (int kb = 0; kb < 16; ++kb) {
        __syncthreads();
        const int k0 = kb * 64;
        #pragma unroll
        for (int i = 0; i < 2; ++i)
            gld16(Ab + (size_t)i * 8 * D_ + k0, &As[(wave * 2 + i) * 512]);
        #pragma unroll
        for (int i = 0; i < 4; ++i)
            gld16(Bb + (size_t)i * 8 * D_ + k0, &Bs[(wave * 4 + i) * 512]);
        __syncthreads();

        #pragma unroll
        for (int ks = 0; ks < 2; ++ks) {
            const int sw = ((ks * 4 + quad) ^ (l16 & 7)) * 8;
            bf16x8 af[2], bfr[4];
            #pragma unroll
            for (int i = 0; i < 2; ++i)
                af[i] = *(const bf16x8*)&As[(wm * 32 + i * 16 + l16) * 64 + sw];
            #pragma unroll
            for (int i = 0; i < 4; ++i)
                bfr[i] = *(const bf16x8*)&Bs[(wn * 64 + i * 16 + l16) * 64 + sw];
            #pragma unroll
            for (int mi = 0; mi < 2; ++mi)
                #pragma unroll
                for (int ni = 0; ni < 4; ++ni)
                    acc[mi][ni] = __builtin_amdgcn_mfma_f32_16x16x32_bf16(
                        af[mi], bfr[ni], acc[mi][ni], 0, 0, 0);
        }
    }

    #pragma unroll
    for (int ni = 0; ni < 4; ++ni) {
        const int n = n0 + wn * 64 + ni * 16 + l16;
        const float bvl = ext_f32 ? ((const float*)bias)[n]
                                  : bs2f(((const short*)bias)[n]);
        #pragma unroll
        for (int mi = 0; mi < 2; ++mi)
            #pragma unroll
            for (int r = 0; r < 4; ++r) {
                const int m = m0 + wm * 32 + mi * 16 + quad * 4 + r;
                const float v = acc[mi][ni][r] + bvl;
                const size_t idx = (size_t)m * D_ + n;
                if (ext_f32) ((float*)C)[idx] = v;
                else         ((short*)C)[idx] = f2bs(v);
            }
    }
}

// ---------------------------------------------------------------------------
// Flash attention. 512-thread blocks (8 waves x 16 q-rows), q-tile 128,
// K-tile 64, grid (32 bh, 16 qt) = 512 blocks -> 4096 waves (2x the old 4-wave
// version; 16 waves/CU). K/V double-buffered in LDS with prefetch issued
// BEFORE compute each iteration (T3 minimal 2-phase) so the vmcnt(0) drain at
// the barrier lands after ~18 MFMA + 16 exp2 of cover. K/V staged via
// global_load_lds + XOR swizzle. S^T = K·Q^T MFMA -> lane has 4 consecutive
// k of one q -> exp2 (scale pre-folded into Q) + perm-pack -> ds_write_b64
// into wave-private Ps. PV and lsum (ones-MFMA) on the same truncated P
// (cancels in O = PV/P1).
// ---------------------------------------------------------------------------
__global__ __launch_bounds__(512) void attn(
    const short* __restrict__ Q, const short* __restrict__ K,
    const short* __restrict__ Vt, short* __restrict__ Aout)
{
    __shared__ __align__(16) short Ks[2][64 * 64];
    __shared__ __align__(16) short Vs[2][64 * 64];
    __shared__ __align__(16) short Ps[8][16 * LDSW];

    const int t = threadIdx.x;
    const int wave = t >> 6, lane = t & 63;
    const int quad = lane >> 4, l16 = lane & 15;
    const int bh = blockIdx.x;          // bh-major: same-head blocks share XCD L2
    const int q0 = blockIdx.y * 128;
    const int lr = lane >> 3;           // [0,8): row within this wave's 8-row stripe
    const int kx = ((lane & 7) ^ (lr & 7)) * 8;
    short* pw = &Ps[wave][0];

    // Q fragment: this wave's 16 q-rows (already scaled by 0.125*log2e)
    bf16x8 bq0, bq1;
    {
        const short* qr = Q + ((size_t)bh * S_ + q0 + wave * 16 + l16) * HD_ + quad * 8;
        bq0 = *(const bf16x8*)qr;
        bq1 = *(const bf16x8*)(qr + 32);
    }

    bf16x8 ones;
    #pragma unroll
    for (int i = 0; i < 8; ++i) ones[i] = (short)0x3F80;  // bf16 1.0

    f32x4 o[4], lacc;
    lacc = (f32x4){0.f, 0.f, 0.f, 0.f};
    #pragma unroll
    for (int nt = 0; nt < 4; ++nt) o[nt] = (f32x4){0.f, 0.f, 0.f, 0.f};

    // each wave stages an 8-row stripe of the 64-row K tile / V (transposed) tile
    const short* Kb = K  + ((size_t)bh * S_  + wave * 8 + lr) * HD_ + kx;
    const short* Vb = Vt + ((size_t)bh * HD_ + wave * 8 + lr) * S_ + kx;

    // prologue: stage tile 0 into buffer 0
    gld16(Kb, &Ks[0][wave * 512]);
    gld16(Vb, &Vs[0][wave * 512]);
    __syncthreads();  // vmcnt(0) drain: buf0 ready

    for (int j = 0; j < 32; ++j) {
        const int cur = j & 1;
        // prefetch next tile into the other buffer (read last at j-1, safe
        // past the barrier); latency hides under this iteration's compute
        if (j < 31) {
            gld16(Kb + (size_t)((j + 1) * 64) * HD_, &Ks[cur ^ 1][wave * 512]);
            gld16(Vb + (j + 1) * 64,                 &Vs[cur ^ 1][wave * 512]);
        }

        // S^T = K . Q^T : lane (quad,l16) gets k = nt*16+quad*4+r, q = l16
        f32x4 st[4];
        #pragma unroll
        for (int nt = 0; nt < 4; ++nt) {
            bf16x8 kf0 = *(const bf16x8*)&Ks[cur][(nt * 16 + l16) * 64 + ((quad ^ (l16 & 7)) * 8)];
            bf16x8 kf1 = *(const bf16x8*)&Ks[cur][(nt * 16 + l16) * 64 + (((4 + quad) ^ (l16 & 7)) * 8)];
            f32x4 z = (f32x4){0.f, 0.f, 0.f, 0.f};
            z = __builtin_amdgcn_mfma_f32_16x16x32_bf16(kf0, bq0, z, 0, 0, 0);
            z = __builtin_amdgcn_mfma_f32_16x16x32_bf16(kf1, bq1, z, 0, 0, 0);
            st[nt] = z;
        }

        // exp2 (scale already folded into Q) + pack to bf16 + scatter to Ps
        #pragma unroll
        for (int nt = 0; nt < 4; ++nt) {
            unsigned u0 = __float_as_uint(__builtin_amdgcn_exp2f(st[nt][0]));
            unsigned u1 = __float_as_uint(__builtin_amdgcn_exp2f(st[nt][1]));
            unsigned u2 = __float_as_uint(__builtin_amdgcn_exp2f(st[nt][2]));
            unsigned u3 = __float_as_uint(__builtin_amdgcn_exp2f(st[nt][3]));
            uint2 pk;
            pk.x = __builtin_amdgcn_perm(u1, u0, 0x07060302);  // [bf16(p1)|bf16(p0)]
            pk.y = __builtin_amdgcn_perm(u3, u2, 0x07060302);
            *(uint2*)&pw[l16 * LDSW + nt * 16 + quad * 4] = pk;
        }
        __builtin_amdgcn_s_waitcnt(0xc07f);  // lgkmcnt(0): Ps is wave-private

        // PV + row-sum (ones-MFMA) on the packed P
        #pragma unroll
        for (int ks = 0; ks < 2; ++ks) {
            bf16x8 vf[4];
            #pragma unroll
            for (int nt = 0; nt < 4; ++nt)
                vf[nt] = *(const bf16x8*)&Vs[cur][(nt * 16 + l16) * 64 + (((ks * 4 + quad) ^ (l16 & 7)) * 8)];
            bf16x8 ap = *(const bf16x8*)&pw[l16 * LDSW + ks * 32 + quad * 8];
            lacc = __builtin_amdgcn_mfma_f32_16x16x32_bf16(ap, ones, lacc, 0, 0, 0);
            #pragma unroll
            for (int nt = 0; nt < 4; ++nt)
                o[nt] = __builtin_amdgcn_mfma_f32_16x16x32_bf16(ap, vf[nt], o[nt], 0, 0, 0);
        }

        __syncthreads();  // drains vmcnt(0): next buffer staged + all reads done
    }

    const int b = bh >> 4, h = bh & 15;
    #pragma unroll
    for (int r = 0; r < 4; ++r) {
        const float inv = 1.f / lacc[r];
        const int s = q0 + wave * 16 + quad * 4 + r;
        const size_t base = ((size_t)b * S_ + s) * D_ + h * HD_;
        #pragma unroll
        for (int nt = 0; nt < 4; ++nt)
            Aout[base + nt * 16 + l16] = f2bs(o[nt][r] * inv);
    }
}

// ---------------------------------------------------------------------------
extern "C" void kernel_launch(void* const* d_in, const int* in_sizes, int n_in,
                              void* d_out, int out_size, void* d_ws, size_t ws_size,
                              hipStream_t stream) {
    char* ws = (char*)d_ws;
    short* Wt  = (short*)(ws + ((size_t)1  << 20));      // 4x[1024][1024] bf16, 8MB
    short* Att = (short*)(ws + ((size_t)9  << 20));      // [4096][1024] bf16, 8MB
    short* QKV = (short*)(ws + ((size_t)17 << 20));      // Q|K|Vt, 24MB
    const unsigned int* xw = (const unsigned int*)d_in[0];

    prep<<<1024, 256, 0, stream>>>(d_in[0], d_in[1], d_in[3], d_in[5], d_in[7], Wt);
    gemm_qkv<<<dim3(32, 24), 256, 0, stream>>>(d_in[0], Wt, d_in[2], d_in[4], d_in[6], QKV);
    attn<<<dim3(32, 16), 512, 0, stream>>>(QKV, QKV + QSZ, QKV + 2 * QSZ, Att);
    gemm_out<<<dim3(64, 8), 256, 0, stream>>>(Att, Wt + (3 << 20), d_in[8], d_out, xw);
}